// Round 11
// baseline (318.316 us; speedup 1.0000x reference)
//
#include <hip/hip_runtime.h>

// MemoryBank contrastive loss, steady state.
// B=1024, D=128, C=50, K=4096, N = C*K = 204800. TEMP=0.3.
// loss = (1/B) * sum_b w_b * ( ln(sum exp(dot/T)) - dot_pos/T )
// SCALE = log2(e)/T folded into normalized bf16 features: MFMA acc feeds exp2.
//
// R15: halve LDS traffic AT 16 waves/CU -- the untried quadrant.
// R14 (acc-dbuf) was null: in-wave ILP isn't the constraint (VGPR 52,
// counters unchanged). Corrected R7 accounting (VALUBusy includes MFMA
// issue on gfx950): LDS-read 31us is the TOP pipe, MFMA 26, VALU ~10,
// HBM ~17; wall 78.6 = 2.5x max pipe. mf=4 halves LDS to 16us; R8 proved
// mf=4 = 96 VGPR spill-free; its failure mode was 8 waves/CU, not regs.
// Geometry never tried: 8 waves x 64 rows = 512 rows/block, y=2, grid
// (256,2) = 512 blocks = 2/CU where the CU's two blocks are SAME-XC
// y-partners (k and k+256 stream identical tiles) -> tile loaded once
// per CU, 2nd block L1-hits; launch_bounds(512,4) = proven 16-waves/CU
// residency, 128-reg cap >= 96 measured. 12.5 phases (vs 25) also halves
// barrier count. nt = 13 (xc<128) / 12.
// Checks: VGPR ~96 + WRITE ~2MB (no spill); FETCH ~52MB (dedupe);
// dur 60-68us if LDS-burst relief real, ~78 null -> deep-pipeline next.
// Keeps: fragment-linear bf16 LDS (0 conflicts, pack-once), T14 split.

#define XCHUNK 256
#define NTILES 3200        // 204800 rows / 64 rows per tile
#define TILE_BYTES 32768   // 64 rows x 128 fp32
#define LN2f 0.6931471805599453f
#define SCALEf 4.808983469629878f   // log2(e)/0.3

typedef __attribute__((ext_vector_type(8))) short bf16x8;
typedef __attribute__((ext_vector_type(4))) float f32x4;
typedef unsigned int u32;

__device__ __forceinline__ unsigned short f2bf(float x) {
    union { float f; unsigned int u; } c; c.f = x;
    unsigned int u = c.u;
    u = (u + 0x7fffu + ((u >> 16) & 1u)) >> 16;   // RNE (features only)
    return (unsigned short)u;
}
__device__ __forceinline__ float bf2f(unsigned short h) {
    union { unsigned int u; float f; } c; c.u = ((unsigned int)h) << 16;
    return c.f;
}
// two fp32 -> two bf16 (truncation) in one v_perm_b32: [bf(lo) | bf(hi)<<16]
__device__ __forceinline__ unsigned int pack_bf2(float lo, float hi) {
    union { float f; unsigned int u; } a, b; a.f = lo; b.f = hi;
    return __builtin_amdgcn_perm(b.u, a.u, 0x07060302u);
}

// ---- Kernel 1: normalize+scale features -> bf16; zero S and out -------------
__global__ void normalize_feat(const float* __restrict__ f,
                               unsigned short* __restrict__ featb,
                               float* __restrict__ S,
                               float* __restrict__ out) {
    const int b = blockIdx.x;          // 1024 blocks
    const int t = threadIdx.x;         // 128 threads
    if (t == 0) S[b] = 0.0f;
    if (b == 0 && t == 1) *out = 0.0f;
    float v = f[b * 128 + t];
    float ss = v * v;
    #pragma unroll
    for (int m = 1; m < 64; m <<= 1) ss += __shfl_xor(ss, m, 64);
    __shared__ float wsum[2];
    if ((t & 63) == 0) wsum[t >> 6] = ss;
    __syncthreads();
    float tot = wsum[0] + wsum[1];
    float inv = SCALEf / fmaxf(sqrtf(tot), 1e-12f);
    featb[b * 128 + t] = f2bf(v * inv);
}

// ---- Kernel 2: fused GEMM + exp2-sum ----------------------------------------
// 512 thr = 8 waves; wave owns 64 m-rows (mf=4), n-tile 64, K=128 complete.
__global__ __launch_bounds__(512, 4) void gemm_lse(
        const unsigned short* __restrict__ featb,  // [1024][128] bf16 (scaled)
        const float* __restrict__ mem,             // [204800][128] fp32
        float* __restrict__ S)                     // [1024] exp2-sums
{
    // 2 x 16 KB bf16 tiles, fragment-linear: slot (nf*4+ks)*64 + lane, 16 B each
    __shared__ uint4 ldsb[2][1024];

    const int tid  = threadIdx.x;
    const int wave = tid >> 6;        // 0..7
    const int lane = tid & 63;
    const int col  = lane & 15;
    const int quad = lane >> 4;

    const int m_wave = blockIdx.y * 512 + wave * 64;
    const int xc = blockIdx.x;        // 0..255
    // 3200 = 256*12 + 128: blocks xc<128 process 13 tiles, others 12
    const int nt = (xc < (NTILES - XCHUNK * 12)) ? 13 : 12;

    // A fragments: A[m=col][k=quad*8+j], mf=4 x ks=4 (64 VGPR)
    bf16x8 afrag[4][4];
    #pragma unroll
    for (int mf = 0; mf < 4; ++mf)
        #pragma unroll
        for (int ks = 0; ks < 4; ++ks)
            afrag[mf][ks] = *(const bf16x8*)&featb[(size_t)(m_wave + mf * 16 + col) * 128
                                                   + ks * 32 + quad * 8];

    float s_part[16];
    #pragma unroll
    for (int i = 0; i < 16; ++i) s_part[i] = 0.0f;

    // Tile-invariant global byte offsets for this thread's two 32 B fp32
    // chunks. Thread t fills LDS slots {t, 512+t} (lane-linear writes); the
    // permutation lives on the GLOBAL side: slot -> (nf,ks,quad,col) ->
    // row (nf*16+col), k-bytes ks*128+quad*32.
    int o[2];
    #pragma unroll
    for (int j = 0; j < 2; ++j) {
        int Sl = j * 512 + tid;           // slot index 0..1023
        int Fi = Sl >> 6, L = Sl & 63;    // fragment id, lane within fragment
        int snf = Fi >> 2, sks = Fi & 3, sq = L >> 4, sc = L & 15;
        o[j] = (snf * 16 + sc) * 512 + sks * 128 + sq * 32;
    }

    // staged registers: 64 B fp32 in flight across COMPUTE (16 VGPR)
    float4 g0a, g0b, g1a, g1b;

    #define LOADS(t_) {                                                         \
        const char* gt = (const char*)mem + (size_t)(xc + XCHUNK * (t_)) * TILE_BYTES; \
        g0a = *(const float4*)(gt + o[0]);                                      \
        g0b = *(const float4*)(gt + o[0] + 16);                                 \
        g1a = *(const float4*)(gt + o[1]);                                      \
        g1b = *(const float4*)(gt + o[1] + 16); }

    #define PACKWRITE(bi) {                                                     \
        uint4 pk;                                                               \
        pk.x = pack_bf2(g0a.x, g0a.y); pk.y = pack_bf2(g0a.z, g0a.w);           \
        pk.z = pack_bf2(g0b.x, g0b.y); pk.w = pack_bf2(g0b.z, g0b.w);           \
        ldsb[bi][tid] = pk;                                                     \
        pk.x = pack_bf2(g1a.x, g1a.y); pk.y = pack_bf2(g1a.z, g1a.w);           \
        pk.z = pack_bf2(g1b.x, g1b.y); pk.w = pack_bf2(g1b.z, g1b.w);           \
        ldsb[bi][512 + tid] = pk; }

    #define COMPUTE(bi) {                                                       \
        _Pragma("unroll")                                                       \
        for (int nf = 0; nf < 4; ++nf) {                                        \
            f32x4 acc[4];                                                       \
            _Pragma("unroll")                                                   \
            for (int mf = 0; mf < 4; ++mf) acc[mf] = (f32x4)(0.0f);             \
            _Pragma("unroll")                                                   \
            for (int ks = 0; ks < 4; ++ks) {                                    \
                bf16x8 bfrag = *(const bf16x8*)&ldsb[bi][(nf * 4 + ks) * 64 + lane]; \
                _Pragma("unroll")                                               \
                for (int mf = 0; mf < 4; ++mf)                                  \
                    acc[mf] = __builtin_amdgcn_mfma_f32_16x16x32_bf16(          \
                        afrag[mf][ks], bfrag, acc[mf], 0, 0, 0);                \
            }                                                                   \
            _Pragma("unroll")                                                   \
            for (int mf = 0; mf < 4; ++mf)                                      \
                _Pragma("unroll")                                               \
                for (int r = 0; r < 4; ++r)                                     \
                    s_part[mf * 4 + r] += __builtin_amdgcn_exp2f(acc[mf][r]);   \
        } }

    // prologue: stage tile 0 into buf0
    LOADS(0)
    PACKWRITE(0)
    __syncthreads();

    for (int t = 0; t < nt; ++t) {
        if (t + 1 < nt) LOADS(t + 1)          // in flight during compute
        COMPUTE(t & 1)
        if (t + 1 < nt) PACKWRITE((t + 1) & 1)     // other buffer; last read 2 barriers ago
        __syncthreads();
    }

    // reduce across the 16 col-lanes sharing the same quad
    #pragma unroll
    for (int d = 1; d < 16; d <<= 1)
        #pragma unroll
        for (int i = 0; i < 16; ++i)
            s_part[i] += __shfl_xor(s_part[i], d, 64);

    if (col == 0) {
        #pragma unroll
        for (int i = 0; i < 16; ++i) {
            int row = m_wave + (i >> 2) * 16 + quad * 4 + (i & 3);
            atomicAdd(&S[row], s_part[i]);
        }
    }
    #undef LOADS
    #undef PACKWRITE
    #undef COMPUTE
}

// ---- Kernel 3: pos logit + weighted mean ------------------------------------
__global__ void finalize_k(const unsigned short* __restrict__ featb,
                           const float* __restrict__ mem,
                           const int* __restrict__ labels,
                           const float* __restrict__ S,
                           float* __restrict__ out) {
    const int wave = threadIdx.x >> 6;
    const int lane = threadIdx.x & 63;
    const int b = blockIdx.x * 4 + wave;          // 256 blocks x 4 waves = 1024
    const int lab = labels[b];
    const float* mrow = mem + (size_t)lab * (4096 * 128);   // memory[lab][0][:]
    float fa = bf2f(featb[b * 128 + lane]);
    float fc = bf2f(featb[b * 128 + lane + 64]);
    float p = fa * mrow[lane] + fc * mrow[lane + 64];       // t_pos (log2 domain)
    #pragma unroll
    for (int m = 1; m < 64; m <<= 1) p += __shfl_xor(p, m, 64);
    if (lane == 0) {
        float w = (lab < 2) ? 1.3f : 1.0f;
        float v = w * LN2f * (log2f(S[b]) - p) * (1.0f / 1024.0f);
        atomicAdd(out, v);
    }
}

extern "C" void kernel_launch(void* const* d_in, const int* in_sizes, int n_in,
                              void* d_out, int out_size, void* d_ws, size_t ws_size,
                              hipStream_t stream) {
    const float* features = (const float*)d_in[0];
    const int*   labels   = (const int*)d_in[1];
    const float* memory   = (const float*)d_in[2];
    float* out = (float*)d_out;

    unsigned short* featb = (unsigned short*)d_ws;               // 256 KiB
    float* S = (float*)((char*)d_ws + 1024 * 128 * 2);           // 1024 floats

    normalize_feat<<<1024, 128, 0, stream>>>(features, featb, S, out);
    gemm_lse<<<dim3(XCHUNK, 2), 512, 0, stream>>>(featb, memory, S);
    finalize_k<<<256, 256, 0, stream>>>(featb, memory, labels, S, out);
}

// Round 12
// 293.840 us; speedup vs baseline: 1.0833x; 1.0833x over previous
//
#include <hip/hip_runtime.h>

// MemoryBank contrastive loss, steady state.
// B=1024, D=128, C=50, K=4096, N = C*K = 204800. TEMP=0.3.
// loss = (1/B) * sum_b w_b * ( ln(sum exp(dot/T)) - dot_pos/T )
// SCALE = log2(e)/T folded into normalized bf16 features: MFMA acc feeds exp2.
//
// R16: attack the 125 us of non-gemm time. Evidence: total - gemm is
// 124.4-128.8 us across EVERY passing round (R5/R7/R8/R14) while the two
// aux kernels account for <15 us of real work -> ~110 us is per-launch /
// graph-node overhead of the 3-kernel pipeline. Gemm ladder has converged
// (R7 78.6 best; mf=4@16w spills: R15 VGPR 64 + WRITE 68 MB under the
// 128-unified-reg budget). So: ONE kernel + one 4.2 KB memset node.
//  - normalize fused: each block computes its y's 256 inv-norms into LDS
//    (redundant per xc, L2-hot, amortized over 25 tiles); afrag built from
//    fp32 features with identical f2bf RNE bits. featb workspace gone.
//  - finalize fused: per-y counter (threadfence+atomicAdd); 128th finisher
//    of each y reduces pos-logits for its 256 rows (8 waves x 32 rows),
//    atomicAdd to a device accumulator; 4th global finisher stores out.
//    Cross-XCD reads via atomicAdd(p,0.0f) (device-coherent). No spinning.
//  - hipMemsetAsync zeroes S+counters each replay (graph-safe, per G9).
// Gemm core is R7 verbatim: grid (128,4)=512 blocks, launch_bounds(512,4)
// = 16 waves/CU, mf=2, NITER=25, fragment-linear bf16 LDS (0 conflicts,
// pack-once), T14 split. Checks: VGPR ~64 (<=128, WRITE ~2MB = no spill),
// FETCH ~53 MB, fused dur 84-92 us. Total 130-150 if overhead is per-node;
// ~200 = fixed-cost -> pivot to 8-phase gemm next.

#define XCHUNK 128
#define NITER 25           // 128 * 25 = 3200 tiles of 64 rows = 204800
#define TILE_BYTES 32768   // 64 rows x 128 fp32
#define LN2f 0.6931471805599453f
#define SCALEf 4.808983469629878f   // log2(e)/0.3

typedef __attribute__((ext_vector_type(8))) short bf16x8;
typedef __attribute__((ext_vector_type(4))) float f32x4;
typedef unsigned int u32;

__device__ __forceinline__ unsigned short f2bf(float x) {
    union { float f; unsigned int u; } c; c.f = x;
    unsigned int u = c.u;
    u = (u + 0x7fffu + ((u >> 16) & 1u)) >> 16;   // RNE (features only)
    return (unsigned short)u;
}
__device__ __forceinline__ float bf2f(unsigned short h) {
    union { unsigned int u; float f; } c; c.u = ((unsigned int)h) << 16;
    return c.f;
}
// two fp32 -> two bf16 (truncation) in one v_perm_b32: [bf(lo) | bf(hi)<<16]
__device__ __forceinline__ unsigned int pack_bf2(float lo, float hi) {
    union { float f; unsigned int u; } a, b; a.f = lo; b.f = hi;
    return __builtin_amdgcn_perm(b.u, a.u, 0x07060302u);
}

// ---- Single fused kernel ----------------------------------------------------
// 512 thr = 8 waves; wave owns 32 m-rows (mf=2), n-tile 64, K=128 complete.
__global__ __launch_bounds__(512, 4) void fused_loss(
        const float* __restrict__ features,   // [1024][128] fp32
        const int*   __restrict__ labels,     // [1024]
        const float* __restrict__ mem,        // [204800][128] fp32
        float* __restrict__ S,                // ws: [1024] exp2-sums (memset 0)
        int*   __restrict__ cnt,              // ws: [4] per-y counters (memset 0)
        int*   __restrict__ gcnt,             // ws: global finisher counter (memset 0)
        float* __restrict__ finacc,           // ws: loss accumulator (memset 0)
        float* __restrict__ out)              // final scalar
{
    // 2 x 16 KB bf16 tiles, fragment-linear: slot (nf*4+ks)*64 + lane, 16 B each
    __shared__ uint4 ldsb[2][1024];
    __shared__ float norms_inv[256];
    __shared__ float fsum[8];
    __shared__ int   isLast;

    const int tid  = threadIdx.x;
    const int wave = tid >> 6;        // 0..7
    const int lane = tid & 63;
    const int col  = lane & 15;
    const int quad = lane >> 4;

    const int y        = blockIdx.y;        // 0..3
    const int base_row = y * 256;
    const int xc       = blockIdx.x;        // 0..127

    // ---- fused normalize: 256 row inv-norms for this y (redundant per xc) ---
    {
        int lr = tid >> 1, h = tid & 1;     // row 0..255, half 0/1
        const float4* fr = (const float4*)features + (size_t)(base_row + lr) * 32 + h * 16;
        float ss = 0.0f;
        #pragma unroll
        for (int j = 0; j < 16; ++j) {
            float4 v = fr[j];
            ss += v.x * v.x + v.y * v.y + v.z * v.z + v.w * v.w;
        }
        ss += __shfl_xor(ss, 1, 64);        // combine the two halves
        if (h == 0) norms_inv[lr] = SCALEf / fmaxf(sqrtf(ss), 1e-12f);
    }
    __syncthreads();

    // A fragments from fp32 features: A[m=col][k=quad*8+j], mf=2 x ks=4
    bf16x8 afrag[2][4];
    #pragma unroll
    for (int mf = 0; mf < 2; ++mf)
        #pragma unroll
        for (int ks = 0; ks < 4; ++ks) {
            int lrow = wave * 32 + mf * 16 + col;
            const float* fp = features + (size_t)(base_row + lrow) * 128 + ks * 32 + quad * 8;
            float4 a = *(const float4*)fp;
            float4 b = *(const float4*)(fp + 4);
            float inv = norms_inv[lrow];
            bf16x8 f;
            f[0] = (short)f2bf(a.x * inv); f[1] = (short)f2bf(a.y * inv);
            f[2] = (short)f2bf(a.z * inv); f[3] = (short)f2bf(a.w * inv);
            f[4] = (short)f2bf(b.x * inv); f[5] = (short)f2bf(b.y * inv);
            f[6] = (short)f2bf(b.z * inv); f[7] = (short)f2bf(b.w * inv);
            afrag[mf][ks] = f;
        }

    float s_part[8];
    #pragma unroll
    for (int i = 0; i < 8; ++i) s_part[i] = 0.0f;

    // Tile-invariant global byte offsets for this thread's two 32 B fp32
    // chunks. Thread t fills LDS slots {t, 512+t} (lane-linear writes); the
    // permutation lives on the GLOBAL side: slot -> (nf,ks,quad,col) ->
    // row (nf*16+col), k-bytes ks*128+quad*32.
    int o[2];
    #pragma unroll
    for (int j = 0; j < 2; ++j) {
        int Sl = j * 512 + tid;           // slot index 0..1023
        int Fi = Sl >> 6, L = Sl & 63;    // fragment id, lane within fragment
        int snf = Fi >> 2, sks = Fi & 3, sq = L >> 4, sc = L & 15;
        o[j] = (snf * 16 + sc) * 512 + sks * 128 + sq * 32;
    }

    // staged registers: 64 B fp32 in flight across COMPUTE (16 VGPR)
    float4 g0a, g0b, g1a, g1b;

    #define LOADS(t_) {                                                         \
        const char* gt = (const char*)mem + (size_t)(xc + XCHUNK * (t_)) * TILE_BYTES; \
        g0a = *(const float4*)(gt + o[0]);                                      \
        g0b = *(const float4*)(gt + o[0] + 16);                                 \
        g1a = *(const float4*)(gt + o[1]);                                      \
        g1b = *(const float4*)(gt + o[1] + 16); }

    #define PACKWRITE(bi) {                                                     \
        uint4 pk;                                                               \
        pk.x = pack_bf2(g0a.x, g0a.y); pk.y = pack_bf2(g0a.z, g0a.w);           \
        pk.z = pack_bf2(g0b.x, g0b.y); pk.w = pack_bf2(g0b.z, g0b.w);           \
        ldsb[bi][tid] = pk;                                                     \
        pk.x = pack_bf2(g1a.x, g1a.y); pk.y = pack_bf2(g1a.z, g1a.w);           \
        pk.z = pack_bf2(g1b.x, g1b.y); pk.w = pack_bf2(g1b.z, g1b.w);           \
        ldsb[bi][512 + tid] = pk; }

    #define COMPUTE(bi) {                                                       \
        _Pragma("unroll")                                                       \
        for (int nf = 0; nf < 4; ++nf) {                                        \
            f32x4 acc[2];                                                       \
            _Pragma("unroll")                                                   \
            for (int mf = 0; mf < 2; ++mf) acc[mf] = (f32x4)(0.0f);             \
            _Pragma("unroll")                                                   \
            for (int ks = 0; ks < 4; ++ks) {                                    \
                bf16x8 bfrag = *(const bf16x8*)&ldsb[bi][(nf * 4 + ks) * 64 + lane]; \
                _Pragma("unroll")                                               \
                for (int mf = 0; mf < 2; ++mf)                                  \
                    acc[mf] = __builtin_amdgcn_mfma_f32_16x16x32_bf16(          \
                        afrag[mf][ks], bfrag, acc[mf], 0, 0, 0);                \
            }                                                                   \
            _Pragma("unroll")                                                   \
            for (int mf = 0; mf < 2; ++mf)                                      \
                _Pragma("unroll")                                               \
                for (int r = 0; r < 4; ++r)                                     \
                    s_part[mf * 4 + r] += __builtin_amdgcn_exp2f(acc[mf][r]);   \
        } }

    // prologue: stage tile 0 into buf0
    LOADS(0)
    PACKWRITE(0)
    __syncthreads();

    for (int t = 0; t < NITER; ++t) {
        if (t + 1 < NITER) LOADS(t + 1)       // in flight during compute
        COMPUTE(t & 1)
        if (t + 1 < NITER) PACKWRITE((t + 1) & 1)  // other buffer; last read 2 barriers ago
        __syncthreads();
    }

    // reduce across the 16 col-lanes sharing the same quad
    #pragma unroll
    for (int d = 1; d < 16; d <<= 1)
        #pragma unroll
        for (int i = 0; i < 8; ++i)
            s_part[i] += __shfl_xor(s_part[i], d, 64);

    if (col == 0) {
        #pragma unroll
        for (int i = 0; i < 8; ++i) {
            int row = base_row + wave * 32 + (i >> 2) * 16 + quad * 4 + (i & 3);
            atomicAdd(&S[row], s_part[i]);
        }
    }

    // ---- fused finalize: last xc-block of this y reduces its 256 rows -------
    __threadfence();
    if (tid == 0) {
        int old = atomicAdd(&cnt[y], 1);
        isLast = (old == 127);
    }
    __syncthreads();

    if (isLast) {
        float acc = 0.0f;
        #pragma unroll 2
        for (int r = 0; r < 32; ++r) {
            int lr  = wave * 32 + r;
            int b   = base_row + lr;
            int lab = labels[b];
            const float* mrow = mem + (size_t)lab * (4096 * 128);  // memory[lab][0][:]
            float inv = norms_inv[lr];
            float fa = bf2f(f2bf(features[(size_t)b * 128 + lane] * inv));
            float fc = bf2f(f2bf(features[(size_t)b * 128 + lane + 64] * inv));
            float p = fa * mrow[lane] + fc * mrow[lane + 64];      // log2 domain
            #pragma unroll
            for (int m = 1; m < 64; m <<= 1) p += __shfl_xor(p, m, 64);
            if (lane == 0) {
                float Sb = atomicAdd(&S[b], 0.0f);   // device-coherent read
                float w  = (lab < 2) ? 1.3f : 1.0f;
                acc += w * (log2f(Sb) - p);
            }
        }
        if (lane == 0) fsum[wave] = acc * LN2f;
        __syncthreads();
        if (tid == 0) {
            float tot = 0.0f;
            #pragma unroll
            for (int i = 0; i < 8; ++i) tot += fsum[i];
            atomicAdd(finacc, tot);
            __threadfence();
            int o2 = atomicAdd(gcnt, 1);
            if (o2 == 3) {                           // 4th and last finisher
                float v = atomicAdd(finacc, 0.0f);   // device-coherent read
                *out = v * (1.0f / 1024.0f);
            }
        }
    }
    #undef LOADS
    #undef PACKWRITE
    #undef COMPUTE
}

extern "C" void kernel_launch(void* const* d_in, const int* in_sizes, int n_in,
                              void* d_out, int out_size, void* d_ws, size_t ws_size,
                              hipStream_t stream) {
    const float* features = (const float*)d_in[0];
    const int*   labels   = (const int*)d_in[1];
    const float* memory   = (const float*)d_in[2];
    float* out = (float*)d_out;

    // ws layout: S[1024] | cnt[4] | gcnt | pad | finacc
    float* S      = (float*)d_ws;                         // 4096 B
    int*   cnt    = (int*)((char*)d_ws + 4096);           // 16 B
    int*   gcnt   = cnt + 4;                              // 4 B
    float* finacc = (float*)(cnt + 6);                    // 4 B (8-byte aligned)

    hipMemsetAsync(d_ws, 0, 4096 + 64, stream);           // graph-capturable
    fused_loss<<<dim3(XCHUNK, 4), 512, 0, stream>>>(
        features, labels, memory, S, cnt, gcnt, finacc, out);
}